// Round 8
// baseline (1775.386 us; speedup 1.0000x reference)
//
#include <hip/hip_runtime.h>
#include <hip/hip_bf16.h>
#include <stdint.h>

// Problem: LELayer_54022098649764 — f32 inputs.
// x: [16384,512] f32, A: [512,512] f32; out: [16384,512] f32 =
//   sum over 10 nearest neighbors (euclidean, excl self, np-f32 semantics) of xW = x@A.
//
// R8 vs R7 (1199 us; knn_coarse 1005 us, FETCH 825 MB, WRITE 140 MB, VGPR 64):
//  - knn_coarse __launch_bounds__(256,4) -> (256,3). The 4-waves/EU bound
//    capped total regs at 128 (unified VGPR+AGPR): acc=64 AGPR left only 64
//    arch regs -> scratch spill (140 MB writes + ~750 MB re-reads per
//    dispatch, 12x FETCH explosion vs R5). At 3 waves/EU the budget is 170:
//    no spill, and 96 resident blocks/XCD puts the L2 working set (A 2 MB +
//    8 parts x B-tile drift) back under the 4 MB per-XCD L2 with headroom.
//    Cost: 1024-block grid at 3/CU has a 256-block tail (~8%) — cheap vs
//    825 MB of off-chip traffic.
//  - Everything else identical to R7 (passed, absmax 1.0): hh-only coarse +
//    exact rerank, packed (qd<<14|col) top-13 lists, counted-vmcnt k-loop,
//    T2 source swizzle, XCD remap, setprio, strip-min scan.

typedef _Float16 f16x8 __attribute__((ext_vector_type(8)));
typedef float f32x4 __attribute__((ext_vector_type(4)));

#define NPTS 16384
#define DIM 512
#define KNN 10
#define TILE 128
#define BK 32
#define NPART 8
#define PARTC (NPTS / NPART)      // 2048
#define NCT (PARTC / TILE)        // 16
#define NKC (DIM / BK)            // 16
#define SET_H (TILE * BK)         // 4096 halfs per tile
#define D2PAD 36
#define CLIST 13                  // coarse candidates per part
#define NCAND (NPART * CLIST)     // 104
#define RCAND 20                  // reranked candidates

// ws layout (bytes), total ~68.2 MB
//  liveness: aht/alt: split_at -> xw | xh: split_x -> knn_coarse |
//  xl: split_x -> xw | pk(=xl): knn_coarse -> rerank | idx(=xh): rerank -> gather
#define OFF_SQ   0u
#define OFF_AHT  65536u
#define OFF_ALT  (OFF_AHT + 524288u)
#define OFF_XH   (OFF_ALT + 524288u)           // 16 MB
#define OFF_IDX  OFF_XH                        // alias
#define OFF_XL   (OFF_XH + 16777216u)          // 16 MB
#define OFF_PK   OFF_XL                        // alias: 8*16384*13*4 = 6.8 MB
#define OFF_XW   (OFF_XL + 16777216u)          // 32 MB

#define GLDS16(g, l) __builtin_amdgcn_global_load_lds( \
    (__attribute__((address_space(1))) const void*)(g), \
    (__attribute__((address_space(3))) void*)(l), 16, 0, 0)

#define WAITVM(N) do { asm volatile("s_waitcnt vmcnt(" #N ")" ::: "memory"); \
                       __builtin_amdgcn_sched_barrier(0); } while (0)
#define WAITLGKM0 do { asm volatile("s_waitcnt lgkmcnt(0)" ::: "memory"); \
                       __builtin_amdgcn_sched_barrier(0); } while (0)

__device__ __forceinline__ float4 min4(float4 a, float4 b) {
  return make_float4(fminf(a.x, b.x), fminf(a.y, b.y), fminf(a.z, b.z), fminf(a.w, b.w));
}

// Full split staging (xw_kernel): [Ah, Al, Bh, Bl] tiles, 8 loads/thread.
__device__ __forceinline__ void stage_tiles(const _Float16* __restrict__ ah,
                                            const _Float16* __restrict__ al,
                                            const _Float16* __restrict__ bh,
                                            const _Float16* __restrict__ bl,
                                            int ar0, int br0, int k0,
                                            _Float16* set, int wv, int lane, int sstk) {
  const int strow = wv * 16 + (lane >> 2);
#pragma unroll
  for (int q = 0; q < 2; q++) {
    const int row = q * 64 + strow;
    const int dst = q * 2048 + wv * 512 + lane * 8;
    const size_t ga = (size_t)(ar0 + row) * DIM + k0 + sstk;
    const size_t gb = (size_t)(br0 + row) * DIM + k0 + sstk;
    GLDS16(ah + ga, set + dst);
    GLDS16(al + ga, set + SET_H + dst);
    GLDS16(bh + gb, set + 2 * SET_H + dst);
    GLDS16(bl + gb, set + 3 * SET_H + dst);
  }
}

// hh-only staging (knn_coarse): [Ah, Bh], 4 loads/thread. Global-source XOR
// swizzle (sstk) keeps LDS dest linear; physical chunk p of row R holds
// logical chunk p^((R>>1)&3), read back with pq8.
__device__ __forceinline__ void stage_h(const _Float16* __restrict__ xh,
                                        int ar0, int br0, int k0,
                                        _Float16* set, int wv, int lane, int sstk) {
  const int strow = wv * 16 + (lane >> 2);
#pragma unroll
  for (int q = 0; q < 2; q++) {
    const int row = q * 64 + strow;
    const int dst = q * 2048 + wv * 512 + lane * 8;
    GLDS16(xh + (size_t)(ar0 + row) * DIM + k0 + sstk, set + dst);
    GLDS16(xh + (size_t)(br0 + row) * DIM + k0 + sstk, set + SET_H + dst);
  }
}

// ---------------- k0: split x -> xh,xl (f16) and sq (f32) ----------------
__global__ __launch_bounds__(64) void split_x_kernel(const float* __restrict__ x,
                                                     _Float16* __restrict__ xh,
                                                     _Float16* __restrict__ xl,
                                                     float* __restrict__ sq) {
  const int row = blockIdx.x, tid = threadIdx.x;
  const float4* p = (const float4*)(x + (size_t)row * DIM);
  float4 a = p[tid * 2], b = p[tid * 2 + 1];
  float v[8] = {a.x, a.y, a.z, a.w, b.x, b.y, b.z, b.w};
  f16x8 h, l;
  float s = 0.f;
#pragma unroll
  for (int i = 0; i < 8; i++) {
    _Float16 hi = (_Float16)v[i];
    h[i] = hi;
    l[i] = (_Float16)(v[i] - (float)hi);
    s += v[i] * v[i];
  }
  *(f16x8*)(xh + (size_t)row * DIM + tid * 8) = h;
  *(f16x8*)(xl + (size_t)row * DIM + tid * 8) = l;
#pragma unroll
  for (int off = 32; off > 0; off >>= 1) s += __shfl_down(s, off);
  if (tid == 0) sq[row] = s;
}

// ---------------- k0b: split+transpose A -> AhT,AlT [n][k] f16 ----------------
__global__ __launch_bounds__(64) void split_at_kernel(const float* __restrict__ A,
                                                      _Float16* __restrict__ aht,
                                                      _Float16* __restrict__ alt) {
  const int n = blockIdx.x, tid = threadIdx.x;
#pragma unroll
  for (int i = 0; i < DIM / 64; i++) {
    const int k = i * 64 + tid;
    float v = A[(size_t)k * DIM + n];
    _Float16 h = (_Float16)v;
    aht[(size_t)n * DIM + k] = h;
    alt[(size_t)n * DIM + k] = (_Float16)(v - (float)h);
  }
}

// ---------------- k2: xW = x @ A via 3-MFMA f16 split, f32 out ----------------
__global__ __launch_bounds__(256, 2) void xw_kernel(const _Float16* __restrict__ xh,
                                                    const _Float16* __restrict__ xl,
                                                    const _Float16* __restrict__ aht,
                                                    const _Float16* __restrict__ alt,
                                                    float* __restrict__ xw) {
  __shared__ __align__(16) _Float16 stage[2][4 * SET_H];  // 64 KB
  const int tid = threadIdx.x;
  const int nb = blockIdx.x & 3;
  const int rbk = blockIdx.x >> 2;
  const int r0 = rbk * TILE, n0 = nb * TILE;
  const int wv = tid >> 6, lane = tid & 63;
  const int wr = (wv & 1) * 64, wc = (wv >> 1) * 64;
  const int cl = lane & 15, quad = lane >> 4;
  const int sstk = ((lane & 3) ^ ((lane >> 3) & 3)) * 8;
  const int pq8 = (quad ^ ((cl >> 1) & 3)) * 8;

  f32x4 acc[4][4];
#pragma unroll
  for (int i = 0; i < 4; i++)
#pragma unroll
    for (int j = 0; j < 4; j++) acc[i][j] = (f32x4){0.f, 0.f, 0.f, 0.f};

  stage_tiles(xh, xl, aht, alt, r0, n0, 0, stage[0], wv, lane, sstk);
  __syncthreads();

#pragma unroll 2
  for (int kc = 0; kc < NKC; kc++) {
    if (kc + 1 < NKC)
      stage_tiles(xh, xl, aht, alt, r0, n0, (kc + 1) * BK, stage[(kc + 1) & 1], wv, lane, sstk);
    const _Float16* S = stage[kc & 1];
    f16x8 ah[4], al[4], bh[4], bl[4];
#pragma unroll
    for (int i = 0; i < 4; i++) {
      ah[i] = *(const f16x8*)(S + (wr + i * 16 + cl) * BK + pq8);
      al[i] = *(const f16x8*)(S + SET_H + (wr + i * 16 + cl) * BK + pq8);
    }
#pragma unroll
    for (int j = 0; j < 4; j++) {
      bh[j] = *(const f16x8*)(S + 2 * SET_H + (wc + j * 16 + cl) * BK + pq8);
      bl[j] = *(const f16x8*)(S + 3 * SET_H + (wc + j * 16 + cl) * BK + pq8);
    }
#pragma unroll
    for (int i = 0; i < 4; i++)
#pragma unroll
      for (int j = 0; j < 4; j++) {
        acc[i][j] = __builtin_amdgcn_mfma_f32_16x16x32_f16(ah[i], bh[j], acc[i][j], 0, 0, 0);
        acc[i][j] = __builtin_amdgcn_mfma_f32_16x16x32_f16(ah[i], bl[j], acc[i][j], 0, 0, 0);
        acc[i][j] = __builtin_amdgcn_mfma_f32_16x16x32_f16(al[i], bh[j], acc[i][j], 0, 0, 0);
      }
    __syncthreads();
  }
#pragma unroll
  for (int i = 0; i < 4; i++)
#pragma unroll
    for (int r = 0; r < 4; r++) {
      const int row = r0 + wr + i * 16 + quad * 4 + r;
#pragma unroll
      for (int j = 0; j < 4; j++)
        xw[(size_t)row * DIM + n0 + wc + j * 16 + cl] = acc[i][j][r];
    }
}

// ---------------- k3: COARSE distances (hh only) + packed top-13 per part ----
__global__ __launch_bounds__(256, 3) void knn_coarse_kernel(const _Float16* __restrict__ xh,
                                                            const float* __restrict__ sq,
                                                            unsigned int* __restrict__ pk) {
  __shared__ __align__(16) _Float16 stage[2][2 * SET_H];  // 32 KB (aliased d2buf)
  __shared__ unsigned int listp[TILE][CLIST];             // 6656 B, packed (qd<<14|col)
  __shared__ float sqA[TILE], sqB[TILE];                  // 1 KB   => 40448 B total

  const int tid = threadIdx.x;
  // XCD-aware remap (bijective over 1024 blocks): XCD k hosts b%8==k ->
  // 16 consecutive row-tiles per XCD (2 MB A-side L2-resident), parts mixed.
  const int b = blockIdx.x;
  const int rb = (b & 7) * 16 + ((b >> 3) & 15);
  const int part = b >> 7;
  const int r0 = rb * TILE;
  const int cbase = part * PARTC;

  if (tid < TILE) {
    sqA[tid] = sq[r0 + tid];
#pragma unroll
    for (int q = 0; q < CLIST; q++) listp[tid][q] = 0xFFFFFFFFu;
  }
  float th = 4096.0f;  // upper bound on acceptable d2 (packed top unpacked+1)/64

  const int wv = tid >> 6, lane = tid & 63;
  const int wr = (wv & 1) * 64, wc = (wv >> 1) * 64;
  const int cl = lane & 15, quad = lane >> 4;
  const int sstk = ((lane & 3) ^ ((lane >> 3) & 3)) * 8;
  const int pq8 = (quad ^ ((cl >> 1) & 3)) * 8;

  float* d2buf = (float*)stage;  // 18,432 B; used only after k-loop drained

  f32x4 acc[4][4];

  for (int ct = 0; ct < NCT; ct++) {
    const int c0 = cbase + ct * TILE;
    __syncthreads();  // prev epilogue done reading d2buf/sqB
    if (tid < TILE) sqB[tid] = sq[c0 + tid];
#pragma unroll
    for (int i = 0; i < 4; i++)
#pragma unroll
      for (int j = 0; j < 4; j++) acc[i][j] = (f32x4){0.f, 0.f, 0.f, 0.f};

    // prologue: 8 loads in flight (2 stages x 4); counted waits retire in order.
    stage_h(xh, r0, c0, 0, stage[0], wv, lane, sstk);
    stage_h(xh, r0, c0, BK, stage[1], wv, lane, sstk);

    for (int kc = 0; kc < NKC; kc++) {
      if (kc < NKC - 1) { WAITVM(4); } else { WAITVM(0); }
      __builtin_amdgcn_s_barrier();  // buf[kc] landed for all waves

      const _Float16* S = stage[kc & 1];
      f16x8 ah[4], bh[4];
#pragma unroll
      for (int i = 0; i < 4; i++)
        ah[i] = *(const f16x8*)(S + (wr + i * 16 + cl) * BK + pq8);
#pragma unroll
      for (int j = 0; j < 4; j++)
        bh[j] = *(const f16x8*)(S + SET_H + (wc + j * 16 + cl) * BK + pq8);
      WAITLGKM0;
      __builtin_amdgcn_s_barrier();  // all waves done reading buf[kc]

      if (kc + 2 < NKC)
        stage_h(xh, r0, c0, (kc + 2) * BK, stage[kc & 1], wv, lane, sstk);

      __builtin_amdgcn_s_setprio(1);
#pragma unroll
      for (int i = 0; i < 4; i++)
#pragma unroll
        for (int j = 0; j < 4; j++)
          acc[i][j] = __builtin_amdgcn_mfma_f32_16x16x32_f16(ah[i], bh[j], acc[i][j], 0, 0, 0);
      __builtin_amdgcn_s_setprio(0);
    }
    // vmcnt==0, all frag reads done -> stage reusable as d2buf.

    // 4 passes over 32-col strips: dump coarse d2 + strip-min reject + insert.
#pragma unroll
    for (int p = 0; p < 4; p++) {
      const int j0 = (p & 1) * 2;
      const bool mine = (p < 2) ? (wc == 0) : (wc == 64);
      if (mine) {
#pragma unroll
        for (int jj = 0; jj < 2; jj++) {
          const int j = j0 + jj;
          const float sb = sqB[wc + j * 16 + cl];
#pragma unroll
          for (int i = 0; i < 4; i++)
#pragma unroll
            for (int r = 0; r < 4; r++) {
              const int row = wr + i * 16 + quad * 4 + r;
              d2buf[row * D2PAD + jj * 16 + cl] =
                  fmaxf(sqA[row] + sb - 2.0f * acc[i][j][r], 0.0f);
            }
        }
      }
      __syncthreads();
      if (tid < TILE) {
        const int rg = r0 + tid;
        const float* drow = d2buf + tid * D2PAD;
        const float4 v0 = *(const float4*)(drow + 0), v1 = *(const float4*)(drow + 4);
        const float4 v2 = *(const float4*)(drow + 8), v3 = *(const float4*)(drow + 12);
        const float4 v4 = *(const float4*)(drow + 16), v5 = *(const float4*)(drow + 20);
        const float4 v6 = *(const float4*)(drow + 24), v7 = *(const float4*)(drow + 28);
        const float4 ma = min4(min4(min4(v0, v1), min4(v2, v3)),
                               min4(min4(v4, v5), min4(v6, v7)));
        const float mmin = fminf(fminf(ma.x, ma.y), fminf(ma.z, ma.w));
        // reject iff qd(mmin) > top_qd: mmin*64 >= top_qd+1 == th*64  (safe)
        if (mmin < th) {
          for (int c = 0; c < 32; c++) {
            const float d2v = drow[c];
            if (d2v >= th) continue;
            const int cg = c0 + p * 32 + c;
            if (cg == rg) continue;
            const unsigned int qd = (unsigned int)(d2v * 64.0f);  // d2<4096 -> 18b
            const unsigned int pv = (qd << 14) | (unsigned int)cg;
            if (pv < listp[tid][CLIST - 1]) {
              int pp = CLIST - 1;
              while (pp > 0 && listp[tid][pp - 1] > pv) {
                listp[tid][pp] = listp[tid][pp - 1];
                pp--;
              }
              listp[tid][pp] = pv;
              th = (float)((listp[tid][CLIST - 1] >> 14) + 1) * 0.015625f;
            }
          }
        }
      }
      __syncthreads();
    }
  }

  if (tid < TILE) {
    const unsigned int base = ((unsigned int)part * NPTS + (r0 + tid)) * CLIST;
#pragma unroll
    for (int q = 0; q < CLIST; q++) pk[base + q] = listp[tid][q];
  }
}

// ---------------- k4: exact rerank of merged top-RCAND of 104 candidates --------
__global__ __launch_bounds__(64) void rerank_kernel(const float* __restrict__ x,
                                                    const float* __restrict__ sq,
                                                    const unsigned int* __restrict__ pk,
                                                    int* __restrict__ idx) {
  __shared__ unsigned int pkL[NCAND];
  __shared__ unsigned short candL[RCAND];
  const int row = blockIdx.x, lane = threadIdx.x;

  // load the 8x13 packed coarse candidates (values unique: low 14 bits = col)
  for (int e = lane; e < NCAND; e += 64) {
    const int part = e / CLIST, pos = e - part * CLIST;
    pkL[e] = pk[((size_t)part * NPTS + row) * CLIST + pos];
  }
  __syncthreads();

  // rank-select top-RCAND of 104
  for (int e = lane; e < NCAND; e += 64) {
    const unsigned int v = pkL[e];
    int rank = 0;
    for (int s = 0; s < NCAND; s++) rank += (pkL[s] < v) ? 1 : 0;
    if (rank < RCAND) candL[rank] = (unsigned short)(v & 0x3FFFu);
  }
  __syncthreads();

  // own row stash: 8 f32/lane
  const float4 xa = *(const float4*)(x + (size_t)row * DIM + lane * 8);
  const float4 xb = *(const float4*)(x + (size_t)row * DIM + lane * 8 + 4);
  const float sqr = sq[row];

  float dl[KNN]; int il[KNN];
#pragma unroll
  for (int q = 0; q < KNN; q++) { dl[q] = INFINITY; il[q] = 0x7fffffff; }

  for (int k = 0; k < RCAND; k++) {
    const int c = candL[k];
    const float4 ya = *(const float4*)(x + (size_t)c * DIM + lane * 8);
    const float4 yb = *(const float4*)(x + (size_t)c * DIM + lane * 8 + 4);
    float p = xa.x * ya.x;
    p = fmaf(xa.y, ya.y, p); p = fmaf(xa.z, ya.z, p); p = fmaf(xa.w, ya.w, p);
    p = fmaf(xb.x, yb.x, p); p = fmaf(xb.y, yb.y, p);
    p = fmaf(xb.z, yb.z, p); p = fmaf(xb.w, yb.w, p);
#pragma unroll
    for (int off = 32; off > 0; off >>= 1) p += __shfl_xor(p, off);
    const float d2 = sqr + sq[c] - 2.0f * p;
    float dd = sqrtf(fmaxf(d2, 0.0f));  // exact reference domain
    int cc = c;
    // swap-chain insertion, tie-break: smaller index first (top_k stability)
#pragma unroll
    for (int q = 0; q < KNN; q++) {
      const bool better = (dd < dl[q]) || (dd == dl[q] && cc < il[q]);
      const float nd = better ? dl[q] : dd;
      const int ni = better ? il[q] : cc;
      dl[q] = better ? dd : dl[q];
      il[q] = better ? cc : il[q];
      dd = nd; cc = ni;
    }
  }
  if (lane == 0) {
#pragma unroll
    for (int q = 0; q < KNN; q++) idx[(size_t)row * KNN + q] = il[q];
  }
}

// ---------------- k5: gather-sum of 10 neighbor rows of xW (f32) ----------------
__global__ __launch_bounds__(128) void gather_kernel(const float* __restrict__ xw,
                                                     const int* __restrict__ idx,
                                                     float* __restrict__ out) {
  const int row = blockIdx.x, tid = threadIdx.x;
  const int* ip = idx + (size_t)row * KNN;
  float4 s = {0.f, 0.f, 0.f, 0.f};
#pragma unroll
  for (int j = 0; j < KNN; j++) {
    const int nb = ip[j] & (NPTS - 1);
    const float4 v = *(const float4*)(xw + (size_t)nb * DIM + tid * 4);
    s.x += v.x; s.y += v.y; s.z += v.z; s.w += v.w;
  }
  *(float4*)(out + (size_t)row * DIM + tid * 4) = s;
}

extern "C" void kernel_launch(void* const* d_in, const int* in_sizes, int n_in,
                              void* d_out, int out_size, void* d_ws, size_t ws_size,
                              hipStream_t stream) {
  const float* x = (const float*)d_in[0];
  const float* A = (const float*)d_in[1];
  float* out = (float*)d_out;
  char* ws = (char*)d_ws;
  float* sq = (float*)(ws + OFF_SQ);
  unsigned int* pk = (unsigned int*)(ws + OFF_PK);
  int* idx = (int*)(ws + OFF_IDX);
  _Float16* xh = (_Float16*)(ws + OFF_XH);
  _Float16* xl = (_Float16*)(ws + OFF_XL);
  _Float16* aht = (_Float16*)(ws + OFF_AHT);
  _Float16* alt = (_Float16*)(ws + OFF_ALT);
  float* xw = (float*)(ws + OFF_XW);

  split_x_kernel<<<NPTS, 64, 0, stream>>>(x, xh, xl, sq);
  split_at_kernel<<<DIM, 64, 0, stream>>>(A, aht, alt);
  xw_kernel<<<(NPTS / TILE) * (DIM / TILE), 256, 0, stream>>>(xh, xl, aht, alt, xw);
  knn_coarse_kernel<<<NPART * (NPTS / TILE), 256, 0, stream>>>(xh, sq, pk);
  rerank_kernel<<<NPTS, 64, 0, stream>>>(x, sq, pk, idx);
  gather_kernel<<<NPTS, 128, 0, stream>>>(xw, idx, out);
}

// Round 12
// 1197.049 us; speedup vs baseline: 1.4831x; 1.4831x over previous
//
#include <hip/hip_runtime.h>
#include <hip/hip_bf16.h>
#include <stdint.h>

// Problem: LELayer_54022098649764 — f32 inputs.
// x: [16384,512] f32, A: [512,512] f32; out: [16384,512] f32 =
//   sum over 10 nearest neighbors (euclidean, excl self, np-f32 semantics) of xW = x@A.
//
// R12 == R9/R10/R11 resubmission (all failed on GPU acquisition infra, not the kernel).
// R9 vs R8 (1641 us regression) / R7 (1005 us):
//  - R8's (256,3) made grid 1024 run in TWO dispatch waves (768 + 256) — the
//    "tail" costs a full wave, not 8%. Revert to (256,4): 1024 blocks = one
//    wave at 4/CU (R7 measured Occ 46.5%).
//  - R7's real problem was scratch spill (WRITE 140 MB, FETCH 825 MB): at
//    (256,4) the unified budget is 128/wave = 64 AGPR acc + 64 arch, and the
//    epilogue scan held 8 float4s (32 regs) live at once. Fix: sequential
//    strip-min in 2-live-float4 chunks, pinned with sched_barrier(0) so the
//    scheduler cannot hoist all 8 LDS loads -> scan pressure ~12 regs ->
//    arch side fits in 64 spill-free.
//  - Everything else identical to R7/R8 (passed, absmax 1.0): hh-only coarse
//    + exact rerank, packed (qd<<14|col) top-13, counted-vmcnt k-loop, T2
//    source swizzle, XCD remap, setprio.

typedef _Float16 f16x8 __attribute__((ext_vector_type(8)));
typedef float f32x4 __attribute__((ext_vector_type(4)));

#define NPTS 16384
#define DIM 512
#define KNN 10
#define TILE 128
#define BK 32
#define NPART 8
#define PARTC (NPTS / NPART)      // 2048
#define NCT (PARTC / TILE)        // 16
#define NKC (DIM / BK)            // 16
#define SET_H (TILE * BK)         // 4096 halfs per tile
#define D2PAD 36
#define CLIST 13                  // coarse candidates per part
#define NCAND (NPART * CLIST)     // 104
#define RCAND 20                  // reranked candidates

// ws layout (bytes), total ~68.2 MB
//  liveness: aht/alt: split_at -> xw | xh: split_x -> knn_coarse |
//  xl: split_x -> xw | pk(=xl): knn_coarse -> rerank | idx(=xh): rerank -> gather
#define OFF_SQ   0u
#define OFF_AHT  65536u
#define OFF_ALT  (OFF_AHT + 524288u)
#define OFF_XH   (OFF_ALT + 524288u)           // 16 MB
#define OFF_IDX  OFF_XH                        // alias
#define OFF_XL   (OFF_XH + 16777216u)          // 16 MB
#define OFF_PK   OFF_XL                        // alias: 8*16384*13*4 = 6.8 MB
#define OFF_XW   (OFF_XL + 16777216u)          // 32 MB

#define GLDS16(g, l) __builtin_amdgcn_global_load_lds( \
    (__attribute__((address_space(1))) const void*)(g), \
    (__attribute__((address_space(3))) void*)(l), 16, 0, 0)

#define WAITVM(N) do { asm volatile("s_waitcnt vmcnt(" #N ")" ::: "memory"); \
                       __builtin_amdgcn_sched_barrier(0); } while (0)
#define WAITLGKM0 do { asm volatile("s_waitcnt lgkmcnt(0)" ::: "memory"); \
                       __builtin_amdgcn_sched_barrier(0); } while (0)

__device__ __forceinline__ float4 min4(float4 a, float4 b) {
  return make_float4(fminf(a.x, b.x), fminf(a.y, b.y), fminf(a.z, b.z), fminf(a.w, b.w));
}

// Full split staging (xw_kernel): [Ah, Al, Bh, Bl] tiles, 8 loads/thread.
__device__ __forceinline__ void stage_tiles(const _Float16* __restrict__ ah,
                                            const _Float16* __restrict__ al,
                                            const _Float16* __restrict__ bh,
                                            const _Float16* __restrict__ bl,
                                            int ar0, int br0, int k0,
                                            _Float16* set, int wv, int lane, int sstk) {
  const int strow = wv * 16 + (lane >> 2);
#pragma unroll
  for (int q = 0; q < 2; q++) {
    const int row = q * 64 + strow;
    const int dst = q * 2048 + wv * 512 + lane * 8;
    const size_t ga = (size_t)(ar0 + row) * DIM + k0 + sstk;
    const size_t gb = (size_t)(br0 + row) * DIM + k0 + sstk;
    GLDS16(ah + ga, set + dst);
    GLDS16(al + ga, set + SET_H + dst);
    GLDS16(bh + gb, set + 2 * SET_H + dst);
    GLDS16(bl + gb, set + 3 * SET_H + dst);
  }
}

// hh-only staging (knn_coarse): [Ah, Bh], 4 loads/thread. Global-source XOR
// swizzle (sstk) keeps LDS dest linear; physical chunk p of row R holds
// logical chunk p^((R>>1)&3), read back with pq8.
__device__ __forceinline__ void stage_h(const _Float16* __restrict__ xh,
                                        int ar0, int br0, int k0,
                                        _Float16* set, int wv, int lane, int sstk) {
  const int strow = wv * 16 + (lane >> 2);
#pragma unroll
  for (int q = 0; q < 2; q++) {
    const int row = q * 64 + strow;
    const int dst = q * 2048 + wv * 512 + lane * 8;
    GLDS16(xh + (size_t)(ar0 + row) * DIM + k0 + sstk, set + dst);
    GLDS16(xh + (size_t)(br0 + row) * DIM + k0 + sstk, set + SET_H + dst);
  }
}

// ---------------- k0: split x -> xh,xl (f16) and sq (f32) ----------------
__global__ __launch_bounds__(64) void split_x_kernel(const float* __restrict__ x,
                                                     _Float16* __restrict__ xh,
                                                     _Float16* __restrict__ xl,
                                                     float* __restrict__ sq) {
  const int row = blockIdx.x, tid = threadIdx.x;
  const float4* p = (const float4*)(x + (size_t)row * DIM);
  float4 a = p[tid * 2], b = p[tid * 2 + 1];
  float v[8] = {a.x, a.y, a.z, a.w, b.x, b.y, b.z, b.w};
  f16x8 h, l;
  float s = 0.f;
#pragma unroll
  for (int i = 0; i < 8; i++) {
    _Float16 hi = (_Float16)v[i];
    h[i] = hi;
    l[i] = (_Float16)(v[i] - (float)hi);
    s += v[i] * v[i];
  }
  *(f16x8*)(xh + (size_t)row * DIM + tid * 8) = h;
  *(f16x8*)(xl + (size_t)row * DIM + tid * 8) = l;
#pragma unroll
  for (int off = 32; off > 0; off >>= 1) s += __shfl_down(s, off);
  if (tid == 0) sq[row] = s;
}

// ---------------- k0b: split+transpose A -> AhT,AlT [n][k] f16 ----------------
__global__ __launch_bounds__(64) void split_at_kernel(const float* __restrict__ A,
                                                      _Float16* __restrict__ aht,
                                                      _Float16* __restrict__ alt) {
  const int n = blockIdx.x, tid = threadIdx.x;
#pragma unroll
  for (int i = 0; i < DIM / 64; i++) {
    const int k = i * 64 + tid;
    float v = A[(size_t)k * DIM + n];
    _Float16 h = (_Float16)v;
    aht[(size_t)n * DIM + k] = h;
    alt[(size_t)n * DIM + k] = (_Float16)(v - (float)h);
  }
}

// ---------------- k2: xW = x @ A via 3-MFMA f16 split, f32 out ----------------
__global__ __launch_bounds__(256, 2) void xw_kernel(const _Float16* __restrict__ xh,
                                                    const _Float16* __restrict__ xl,
                                                    const _Float16* __restrict__ aht,
                                                    const _Float16* __restrict__ alt,
                                                    float* __restrict__ xw) {
  __shared__ __align__(16) _Float16 stage[2][4 * SET_H];  // 64 KB
  const int tid = threadIdx.x;
  const int nb = blockIdx.x & 3;
  const int rbk = blockIdx.x >> 2;
  const int r0 = rbk * TILE, n0 = nb * TILE;
  const int wv = tid >> 6, lane = tid & 63;
  const int wr = (wv & 1) * 64, wc = (wv >> 1) * 64;
  const int cl = lane & 15, quad = lane >> 4;
  const int sstk = ((lane & 3) ^ ((lane >> 3) & 3)) * 8;
  const int pq8 = (quad ^ ((cl >> 1) & 3)) * 8;

  f32x4 acc[4][4];
#pragma unroll
  for (int i = 0; i < 4; i++)
#pragma unroll
    for (int j = 0; j < 4; j++) acc[i][j] = (f32x4){0.f, 0.f, 0.f, 0.f};

  stage_tiles(xh, xl, aht, alt, r0, n0, 0, stage[0], wv, lane, sstk);
  __syncthreads();

#pragma unroll 2
  for (int kc = 0; kc < NKC; kc++) {
    if (kc + 1 < NKC)
      stage_tiles(xh, xl, aht, alt, r0, n0, (kc + 1) * BK, stage[(kc + 1) & 1], wv, lane, sstk);
    const _Float16* S = stage[kc & 1];
    f16x8 ah[4], al[4], bh[4], bl[4];
#pragma unroll
    for (int i = 0; i < 4; i++) {
      ah[i] = *(const f16x8*)(S + (wr + i * 16 + cl) * BK + pq8);
      al[i] = *(const f16x8*)(S + SET_H + (wr + i * 16 + cl) * BK + pq8);
    }
#pragma unroll
    for (int j = 0; j < 4; j++) {
      bh[j] = *(const f16x8*)(S + 2 * SET_H + (wc + j * 16 + cl) * BK + pq8);
      bl[j] = *(const f16x8*)(S + 3 * SET_H + (wc + j * 16 + cl) * BK + pq8);
    }
#pragma unroll
    for (int i = 0; i < 4; i++)
#pragma unroll
      for (int j = 0; j < 4; j++) {
        acc[i][j] = __builtin_amdgcn_mfma_f32_16x16x32_f16(ah[i], bh[j], acc[i][j], 0, 0, 0);
        acc[i][j] = __builtin_amdgcn_mfma_f32_16x16x32_f16(ah[i], bl[j], acc[i][j], 0, 0, 0);
        acc[i][j] = __builtin_amdgcn_mfma_f32_16x16x32_f16(al[i], bh[j], acc[i][j], 0, 0, 0);
      }
    __syncthreads();
  }
#pragma unroll
  for (int i = 0; i < 4; i++)
#pragma unroll
    for (int r = 0; r < 4; r++) {
      const int row = r0 + wr + i * 16 + quad * 4 + r;
#pragma unroll
      for (int j = 0; j < 4; j++)
        xw[(size_t)row * DIM + n0 + wc + j * 16 + cl] = acc[i][j][r];
    }
}

// ---------------- k3: COARSE distances (hh only) + packed top-13 per part ----
__global__ __launch_bounds__(256, 4) void knn_coarse_kernel(const _Float16* __restrict__ xh,
                                                            const float* __restrict__ sq,
                                                            unsigned int* __restrict__ pk) {
  __shared__ __align__(16) _Float16 stage[2][2 * SET_H];  // 32 KB (aliased d2buf)
  __shared__ unsigned int listp[TILE][CLIST];             // 6656 B, packed (qd<<14|col)
  __shared__ float sqA[TILE], sqB[TILE];                  // 1 KB   => 40448 B total

  const int tid = threadIdx.x;
  // XCD-aware remap (bijective over 1024 blocks): XCD k hosts b%8==k ->
  // 16 consecutive row-tiles per XCD (2 MB A-side L2-resident), parts mixed.
  const int b = blockIdx.x;
  const int rb = (b & 7) * 16 + ((b >> 3) & 15);
  const int part = b >> 7;
  const int r0 = rb * TILE;
  const int cbase = part * PARTC;

  if (tid < TILE) {
    sqA[tid] = sq[r0 + tid];
#pragma unroll
    for (int q = 0; q < CLIST; q++) listp[tid][q] = 0xFFFFFFFFu;
  }
  float th = 4096.0f;  // upper bound on acceptable d2 (packed top unpacked+1)/64

  const int wv = tid >> 6, lane = tid & 63;
  const int wr = (wv & 1) * 64, wc = (wv >> 1) * 64;
  const int cl = lane & 15, quad = lane >> 4;
  const int sstk = ((lane & 3) ^ ((lane >> 3) & 3)) * 8;
  const int pq8 = (quad ^ ((cl >> 1) & 3)) * 8;

  float* d2buf = (float*)stage;  // 18,432 B; used only after k-loop drained

  f32x4 acc[4][4];

  for (int ct = 0; ct < NCT; ct++) {
    const int c0 = cbase + ct * TILE;
    __syncthreads();  // prev epilogue done reading d2buf/sqB
    if (tid < TILE) sqB[tid] = sq[c0 + tid];
#pragma unroll
    for (int i = 0; i < 4; i++)
#pragma unroll
      for (int j = 0; j < 4; j++) acc[i][j] = (f32x4){0.f, 0.f, 0.f, 0.f};

    // prologue: 8 loads in flight (2 stages x 4); counted waits retire in order.
    stage_h(xh, r0, c0, 0, stage[0], wv, lane, sstk);
    stage_h(xh, r0, c0, BK, stage[1], wv, lane, sstk);

    for (int kc = 0; kc < NKC; kc++) {
      if (kc < NKC - 1) { WAITVM(4); } else { WAITVM(0); }
      __builtin_amdgcn_s_barrier();  // buf[kc] landed for all waves

      const _Float16* S = stage[kc & 1];
      f16x8 ah[4], bh[4];
#pragma unroll
      for (int i = 0; i < 4; i++)
        ah[i] = *(const f16x8*)(S + (wr + i * 16 + cl) * BK + pq8);
#pragma unroll
      for (int j = 0; j < 4; j++)
        bh[j] = *(const f16x8*)(S + SET_H + (wc + j * 16 + cl) * BK + pq8);
      WAITLGKM0;
      __builtin_amdgcn_s_barrier();  // all waves done reading buf[kc]

      if (kc + 2 < NKC)
        stage_h(xh, r0, c0, (kc + 2) * BK, stage[kc & 1], wv, lane, sstk);

      __builtin_amdgcn_s_setprio(1);
#pragma unroll
      for (int i = 0; i < 4; i++)
#pragma unroll
        for (int j = 0; j < 4; j++)
          acc[i][j] = __builtin_amdgcn_mfma_f32_16x16x32_f16(ah[i], bh[j], acc[i][j], 0, 0, 0);
      __builtin_amdgcn_s_setprio(0);
    }
    // vmcnt==0, all frag reads done -> stage reusable as d2buf.

    // 4 passes over 32-col strips: dump coarse d2 + strip-min reject + insert.
#pragma unroll
    for (int p = 0; p < 4; p++) {
      const int j0 = (p & 1) * 2;
      const bool mine = (p < 2) ? (wc == 0) : (wc == 64);
      if (mine) {
#pragma unroll
        for (int jj = 0; jj < 2; jj++) {
          const int j = j0 + jj;
          const float sb = sqB[wc + j * 16 + cl];
#pragma unroll
          for (int i = 0; i < 4; i++)
#pragma unroll
            for (int r = 0; r < 4; r++) {
              const int row = wr + i * 16 + quad * 4 + r;
              d2buf[row * D2PAD + jj * 16 + cl] =
                  fmaxf(sqA[row] + sb - 2.0f * acc[i][j][r], 0.0f);
            }
        }
      }
      __syncthreads();
      if (tid < TILE) {
        const int rg = r0 + tid;
        const float* drow = d2buf + tid * D2PAD;
        // Sequential strip-min, 2 float4s live max. sched_barrier(0) pins the
        // LDS loads so the scheduler can't hoist all 8 (the R7 spill source:
        // 32 live regs in a 64-arch-reg budget).
        float4 m = min4(*(const float4*)(drow + 0), *(const float4*)(drow + 4));
        __builtin_amdgcn_sched_barrier(0);
        m = min4(m, min4(*(const float4*)(drow + 8), *(const float4*)(drow + 12)));
        __builtin_amdgcn_sched_barrier(0);
        m = min4(m, min4(*(const float4*)(drow + 16), *(const float4*)(drow + 20)));
        __builtin_amdgcn_sched_barrier(0);
        m = min4(m, min4(*(const float4*)(drow + 24), *(const float4*)(drow + 28)));
        const float mmin = fminf(fminf(m.x, m.y), fminf(m.z, m.w));
        // reject iff qd(mmin) > top_qd: mmin*64 >= top_qd+1 == th*64  (safe)
        if (mmin < th) {
          for (int c = 0; c < 32; c++) {
            const float d2v = drow[c];
            if (d2v >= th) continue;
            const int cg = c0 + p * 32 + c;
            if (cg == rg) continue;
            const unsigned int qd = (unsigned int)(d2v * 64.0f);  // d2<4096 -> 18b
            const unsigned int pv = (qd << 14) | (unsigned int)cg;
            if (pv < listp[tid][CLIST - 1]) {
              int pp = CLIST - 1;
              while (pp > 0 && listp[tid][pp - 1] > pv) {
                listp[tid][pp] = listp[tid][pp - 1];
                pp--;
              }
              listp[tid][pp] = pv;
              th = (float)((listp[tid][CLIST - 1] >> 14) + 1) * 0.015625f;
            }
          }
        }
      }
      __syncthreads();
    }
  }

  if (tid < TILE) {
    const unsigned int base = ((unsigned int)part * NPTS + (r0 + tid)) * CLIST;
#pragma unroll
    for (int q = 0; q < CLIST; q++) pk[base + q] = listp[tid][q];
  }
}

// ---------------- k4: exact rerank of merged top-RCAND of 104 candidates --------
__global__ __launch_bounds__(64) void rerank_kernel(const float* __restrict__ x,
                                                    const float* __restrict__ sq,
                                                    const unsigned int* __restrict__ pk,
                                                    int* __restrict__ idx) {
  __shared__ unsigned int pkL[NCAND];
  __shared__ unsigned short candL[RCAND];
  const int row = blockIdx.x, lane = threadIdx.x;

  // load the 8x13 packed coarse candidates (values unique: low 14 bits = col)
  for (int e = lane; e < NCAND; e += 64) {
    const int part = e / CLIST, pos = e - part * CLIST;
    pkL[e] = pk[((size_t)part * NPTS + row) * CLIST + pos];
  }
  __syncthreads();

  // rank-select top-RCAND of 104
  for (int e = lane; e < NCAND; e += 64) {
    const unsigned int v = pkL[e];
    int rank = 0;
    for (int s = 0; s < NCAND; s++) rank += (pkL[s] < v) ? 1 : 0;
    if (rank < RCAND) candL[rank] = (unsigned short)(v & 0x3FFFu);
  }
  __syncthreads();

  // own row stash: 8 f32/lane
  const float4 xa = *(const float4*)(x + (size_t)row * DIM + lane * 8);
  const float4 xb = *(const float4*)(x + (size_t)row * DIM + lane * 8 + 4);
  const float sqr = sq[row];

  float dl[KNN]; int il[KNN];
#pragma unroll
  for (int q = 0; q < KNN; q++) { dl[q] = INFINITY; il[q] = 0x7fffffff; }

  for (int k = 0; k < RCAND; k++) {
    const int c = candL[k];
    const float4 ya = *(const float4*)(x + (size_t)c * DIM + lane * 8);
    const float4 yb = *(const float4*)(x + (size_t)c * DIM + lane * 8 + 4);
    float p = xa.x * ya.x;
    p = fmaf(xa.y, ya.y, p); p = fmaf(xa.z, ya.z, p); p = fmaf(xa.w, ya.w, p);
    p = fmaf(xb.x, yb.x, p); p = fmaf(xb.y, yb.y, p);
    p = fmaf(xb.z, yb.z, p); p = fmaf(xb.w, yb.w, p);
#pragma unroll
    for (int off = 32; off > 0; off >>= 1) p += __shfl_xor(p, off);
    const float d2 = sqr + sq[c] - 2.0f * p;
    float dd = sqrtf(fmaxf(d2, 0.0f));  // exact reference domain
    int cc = c;
    // swap-chain insertion, tie-break: smaller index first (top_k stability)
#pragma unroll
    for (int q = 0; q < KNN; q++) {
      const bool better = (dd < dl[q]) || (dd == dl[q] && cc < il[q]);
      const float nd = better ? dl[q] : dd;
      const int ni = better ? il[q] : cc;
      dl[q] = better ? dd : dl[q];
      il[q] = better ? cc : il[q];
      dd = nd; cc = ni;
    }
  }
  if (lane == 0) {
#pragma unroll
    for (int q = 0; q < KNN; q++) idx[(size_t)row * KNN + q] = il[q];
  }
}

// ---------------- k5: gather-sum of 10 neighbor rows of xW (f32) ----------------
__global__ __launch_bounds__(128) void gather_kernel(const float* __restrict__ xw,
                                                     const int* __restrict__ idx,
                                                     float* __restrict__ out) {
  const int row = blockIdx.x, tid = threadIdx.x;
  const int* ip = idx + (size_t)row * KNN;
  float4 s = {0.f, 0.f, 0.f, 0.f};
#pragma unroll
  for (int j = 0; j < KNN; j++) {
    const int nb = ip[j] & (NPTS - 1);
    const float4 v = *(const float4*)(xw + (size_t)nb * DIM + tid * 4);
    s.x += v.x; s.y += v.y; s.z += v.z; s.w += v.w;
  }
  *(float4*)(out + (size_t)row * DIM + tid * 4) = s;
}

extern "C" void kernel_launch(void* const* d_in, const int* in_sizes, int n_in,
                              void* d_out, int out_size, void* d_ws, size_t ws_size,
                              hipStream_t stream) {
  const float* x = (const float*)d_in[0];
  const float* A = (const float*)d_in[1];
  float* out = (float*)d_out;
  char* ws = (char*)d_ws;
  float* sq = (float*)(ws + OFF_SQ);
  unsigned int* pk = (unsigned int*)(ws + OFF_PK);
  int* idx = (int*)(ws + OFF_IDX);
  _Float16* xh = (_Float16*)(ws + OFF_XH);
  _Float16* xl = (_Float16*)(ws + OFF_XL);
  _Float16* aht = (_Float16*)(ws + OFF_AHT);
  _Float16* alt = (_Float16*)(ws + OFF_ALT);
  float* xw = (float*)(ws + OFF_XW);

  split_x_kernel<<<NPTS, 64, 0, stream>>>(x, xh, xl, sq);
  split_at_kernel<<<DIM, 64, 0, stream>>>(A, aht, alt);
  xw_kernel<<<(NPTS / TILE) * (DIM / TILE), 256, 0, stream>>>(xh, xl, aht, alt, xw);
  knn_coarse_kernel<<<NPART * (NPTS / TILE), 256, 0, stream>>>(xh, sq, pk);
  rerank_kernel<<<NPTS, 64, 0, stream>>>(x, sq, pk, idx);
  gather_kernel<<<NPTS, 128, 0, stream>>>(xw, idx, out);
}